// Round 9
// baseline (239.354 us; speedup 1.0000x reference)
//
#include <hip/hip_runtime.h>
#include <hip/hip_bf16.h>
#include <stdint.h>

// ContrastiveLoss: sum over edges of -log( exp(pos)/ (exp(pos)+sum exp(neg)) + 1e-8 )
// with L2-normalized embeddings, temperature 0.5, and JAX-threefry negative sampling.
// Round 2 passed with absmax=0.0 — RNG + numeric ordering below must stay bit-identical.
#define JAX_THREEFRY_PARTITIONABLE 1

struct U2 { uint32_t a, b; };

__host__ __device__ constexpr uint32_t rotl32(uint32_t v, int r) {
    return (v << r) | (v >> (32 - r));
}

__host__ __device__ constexpr U2 tf2x32(uint32_t k0, uint32_t k1, uint32_t x0, uint32_t x1) {
    const uint32_t ks2 = k0 ^ k1 ^ 0x1BD11BDAu;
    const uint32_t ks[3] = {k0, k1, ks2};
    const int rot[2][4] = {{13, 15, 26, 6}, {17, 29, 16, 24}};
    x0 += ks[0]; x1 += ks[1];
    #pragma unroll
    for (int j = 1; j <= 5; ++j) {
        const int* rr = rot[(j - 1) & 1];
        #pragma unroll
        for (int q = 0; q < 4; ++q) { x0 += x1; x1 = rotl32(x1, rr[q]); x1 ^= x0; }
        x0 += ks[j % 3];
        x1 += ks[(j + 1) % 3] + (uint32_t)j;
    }
    return {x0, x1};
}

#if JAX_THREEFRY_PARTITIONABLE
constexpr U2 KEY_HI = tf2x32(0u, 42u, 0u, 0u);
constexpr U2 KEY_LO = tf2x32(0u, 42u, 0u, 1u);
#else
constexpr U2 ENC02 = tf2x32(0u, 42u, 0u, 2u);
constexpr U2 ENC13 = tf2x32(0u, 42u, 1u, 3u);
constexpr U2 KEY_HI = {ENC02.a, ENC13.a};
constexpr U2 KEY_LO = {ENC02.b, ENC13.b};
#endif

__device__ __forceinline__ uint32_t draw_bits(uint32_t ka, uint32_t kb, uint32_t i, uint32_t half) {
#if JAX_THREEFRY_PARTITIONABLE
    U2 o = tf2x32(ka, kb, 0u, i);
    return o.a ^ o.b;
#else
    if (i < half) { return tf2x32(ka, kb, i, i + half).a; }
    else          { return tf2x32(ka, kb, i - half, i).b; }
#endif
}

// DPP-based 16-lane sum. Bit-identical to shfl_xor tree with masks 1,2,4,8:
//  xor1 -> quad_perm [1,0,3,2] (0xB1); xor2 -> quad_perm [2,3,0,1] (0x4E);
//  xor4 -> row_half_mirror (0x141): after xor1+xor2 the partial sum is
//          bitwise-constant within each quad, so the mirrored value equals
//          the xor4 partner bitwise.
//  xor8 -> row_mirror (0x140): same argument at half-row granularity.
// CTRL must be a template arg: __builtin_amdgcn_update_dpp requires an
// integer constant expression (round-6 compile failure with a param).
template <int CTRL>
__device__ __forceinline__ float dpp_add(float v) {
    int t = __builtin_amdgcn_update_dpp(0, __float_as_int(v), CTRL, 0xf, 0xf, false);
    return v + __int_as_float(t);
}

__device__ __forceinline__ float group16_sum(float v) {
    v = dpp_add<0xB1>(v);   // quad_perm xor1
    v = dpp_add<0x4E>(v);   // quad_perm xor2
    v = dpp_add<0x141>(v);  // row_half_mirror == xor4 bitwise
    v = dpp_add<0x140>(v);  // row_mirror == xor8 bitwise
    return v;
}

__device__ __forceinline__ float dot4(const float4& a, const float4& b) {
    return a.x * b.x + a.y * b.y + a.z * b.z + a.w * b.w;
}

// ---------------- Kernel 1: inverse L2 norms ----------------
__global__ __launch_bounds__(256) void inv_norm_kernel(const float* __restrict__ emb,
                                                       float* __restrict__ invn, int N) {
    const int tid = threadIdx.x;
    const int g = tid >> 4, sl = tid & 15;
    const int row = blockIdx.x * 16 + g;
    if (row >= N) return;
    float4 v = *reinterpret_cast<const float4*>(emb + (size_t)row * 64 + sl * 4);
    float ss = dot4(v, v);
    ss = group16_sum(ss);
    if (sl == 0) invn[row] = 1.0f / fmaxf(sqrtf(ss), 1e-12f);
}

// ---------------- Kernel 2: per-edge loss, per-block partial sums ----------------
__global__ __launch_bounds__(256) void edge_loss_kernel(
    const float* __restrict__ emb, const int* __restrict__ ei,
    const float* __restrict__ invn, float* __restrict__ partial,
    int E, uint32_t span, uint32_t mult, uint32_t half,
    uint32_t k1a, uint32_t k1b, uint32_t k2a, uint32_t k2b) {
    const int tid = threadIdx.x;
    const int g = tid >> 4;          // group (edge) within block
    const int sl = tid & 15;         // sublane within group
    const int lane = tid & 63;       // lane within wave
    const int e = blockIdx.x * 16 + g;

    float loss = 0.0f;
    if (e < E) {
        const int s = ei[e];
        const int d = ei[E + e];
        const float inv_s = invn[s];
        const float inv_d = invn[d];
        const float* rowp = emb + sl * 4;
        const float4 sv = *reinterpret_cast<const float4*>(rowp + (size_t)s * 64);
        const float4 dv = *reinterpret_cast<const float4*>(rowp + (size_t)d * 64);

        // negative index for slot sl (computed on all lanes; only sl<10 consumed)
        const int a = min(s, d);
        const int b = max(s, d);
        const uint32_t i = (uint32_t)e * 10u + (uint32_t)sl;
        uint32_t off = draw_bits(k2a, k2b, i, half) % span;  // lower bits
        if (mult != 0u) {
            uint32_t hi = draw_bits(k1a, k1b, i, half) % span;
            off = (hi * mult + off) % span;   // uint32 wrap == lax semantics
        }
        int r = (int)off;
        int r1 = r + (r >= a ? 1 : 0);                        // skip a
        const int negidx = r1 + (((a != b) && (r1 >= b)) ? 1 : 0); // skip b if distinct

        // broadcast all 10 indices to the whole 16-lane group
        int idx[10];
        #pragma unroll
        for (int k = 0; k < 10; ++k) idx[k] = __shfl(negidx, (lane & 48) | k);

        // issue ALL gathers before consuming anything (10 row loads + 10 invn)
        float4 nv[10];
        float ri[10];
        #pragma unroll
        for (int k = 0; k < 10; ++k) {
            nv[k] = *reinterpret_cast<const float4*>(rowp + (size_t)idx[k] * 64);
            ri[k] = invn[idx[k]];
        }

        // positive similarity (same op order as round 2: bit-exact)
        float p = dot4(sv, dv);
        p = group16_sum(p);
        const float pos = p * inv_s * inv_d * 2.0f;  // /T, T=0.5

        float m = pos;
        float ns[10];
        #pragma unroll
        for (int k = 0; k < 10; ++k) {
            float q = dot4(sv, nv[k]);
            q = group16_sum(q);
            const float nsim = q * inv_s * ri[k] * 2.0f;
            ns[k] = nsim;
            m = fmaxf(m, nsim);
        }
        float ssum = expf(pos - m);
        #pragma unroll
        for (int k = 0; k < 10; ++k) ssum += expf(ns[k] - m);
        const float lse = m + logf(ssum);
        const float ratio = expf(pos - lse);
        loss = -logf(ratio + 1e-8f);
    }

    // block reduction: group leaders -> wave sum -> LDS -> partial[block]
    float v = (sl == 0) ? loss : 0.0f;
    v += __shfl_xor(v, 16);
    v += __shfl_xor(v, 32);
    __shared__ float sred[4];
    const int wid = tid >> 6;
    if (lane == 0) sred[wid] = v;
    __syncthreads();
    if (tid == 0) partial[blockIdx.x] = sred[0] + sred[1] + sred[2] + sred[3];
}

// ---------------- Kernel 3: deterministic final reduce (double) ----------------
__global__ __launch_bounds__(256) void finalize_kernel(const float* __restrict__ partial,
                                                       int n, float* __restrict__ out) {
    __shared__ double sd[256];
    double acc = 0.0;
    for (int i = threadIdx.x; i < n; i += 256) acc += (double)partial[i];
    sd[threadIdx.x] = acc;
    __syncthreads();
    for (int s = 128; s > 0; s >>= 1) {
        if (threadIdx.x < s) sd[threadIdx.x] += sd[threadIdx.x + s];
        __syncthreads();
    }
    if (threadIdx.x == 0) out[0] = (float)sd[0];
}

extern "C" void kernel_launch(void* const* d_in, const int* in_sizes, int n_in,
                              void* d_out, int out_size, void* d_ws, size_t ws_size,
                              hipStream_t stream) {
    const float* emb = (const float*)d_in[0];
    const int* ei = (const int*)d_in[1];
    const int N = in_sizes[0] / 64;   // 100000
    const int E = in_sizes[1] / 2;    // 400000
    const int K = 10;                  // K_NEG fixed by problem definition

    float* invn = (float*)d_ws;                 // N floats
    float* partial = invn + N;                  // nblk floats

    const int nblk_main = (E + 15) / 16;
    const int nblk_norm = (N + 15) / 16;

    const uint32_t span = (uint32_t)(N - 2);    // 99998
    const uint32_t m0 = 65536u % span;
    const uint32_t mult = (uint32_t)(m0 * m0) % span;  // wraps mod 2^32 like lax => 0 here
    const uint32_t half = (uint32_t)((E * K) / 2);     // only used by non-partitionable path

    inv_norm_kernel<<<nblk_norm, 256, 0, stream>>>(emb, invn, N);
    edge_loss_kernel<<<nblk_main, 256, 0, stream>>>(emb, ei, invn, partial,
                                                    E, span, mult, half,
                                                    KEY_HI.a, KEY_HI.b, KEY_LO.a, KEY_LO.b);
    finalize_kernel<<<1, 256, 0, stream>>>(partial, nblk_main, (float*)d_out);
}

// Round 13
// 161.470 us; speedup vs baseline: 1.4823x; 1.4823x over previous
//
#include <hip/hip_runtime.h>
#include <hip/hip_bf16.h>
#include <stdint.h>

// ContrastiveLoss: sum over edges of -log( exp(pos)/(exp(pos)+sum exp(neg)) + 1e-8 )
// Round 9 evidence: two schedule variants -> identical 143us / 520MB fetch /
// 3.73 TB/s => bound by L2-miss byte traffic (per-XCD 4MB L2 vs 26MB table).
// Round 10 lever: pre-normalized bf16 table in d_ws (12.8MB): halves gathered
// bytes, doubles L2 hit rate, kills the invn gathers. f32 bit-exact path kept
// as ws_size fallback / tolerance revert.
#define JAX_THREEFRY_PARTITIONABLE 1

struct U2 { uint32_t a, b; };

__host__ __device__ constexpr uint32_t rotl32(uint32_t v, int r) {
    return (v << r) | (v >> (32 - r));
}

__host__ __device__ constexpr U2 tf2x32(uint32_t k0, uint32_t k1, uint32_t x0, uint32_t x1) {
    const uint32_t ks2 = k0 ^ k1 ^ 0x1BD11BDAu;
    const uint32_t ks[3] = {k0, k1, ks2};
    const int rot[2][4] = {{13, 15, 26, 6}, {17, 29, 16, 24}};
    x0 += ks[0]; x1 += ks[1];
    #pragma unroll
    for (int j = 1; j <= 5; ++j) {
        const int* rr = rot[(j - 1) & 1];
        #pragma unroll
        for (int q = 0; q < 4; ++q) { x0 += x1; x1 = rotl32(x1, rr[q]); x1 ^= x0; }
        x0 += ks[j % 3];
        x1 += ks[(j + 1) % 3] + (uint32_t)j;
    }
    return {x0, x1};
}

#if JAX_THREEFRY_PARTITIONABLE
constexpr U2 KEY_HI = tf2x32(0u, 42u, 0u, 0u);
constexpr U2 KEY_LO = tf2x32(0u, 42u, 0u, 1u);
#else
constexpr U2 ENC02 = tf2x32(0u, 42u, 0u, 2u);
constexpr U2 ENC13 = tf2x32(0u, 42u, 1u, 3u);
constexpr U2 KEY_HI = {ENC02.a, ENC13.a};
constexpr U2 KEY_LO = {ENC02.b, ENC13.b};
#endif

__device__ __forceinline__ uint32_t draw_bits(uint32_t ka, uint32_t kb, uint32_t i, uint32_t half) {
#if JAX_THREEFRY_PARTITIONABLE
    U2 o = tf2x32(ka, kb, 0u, i);
    return o.a ^ o.b;
#else
    if (i < half) { return tf2x32(ka, kb, i, i + half).a; }
    else          { return tf2x32(ka, kb, i - half, i).b; }
#endif
}

// DPP 16-lane sum, bit-identical to shfl_xor{1,2,4,8} (see round-6/7 notes).
template <int CTRL>
__device__ __forceinline__ float dpp_add(float v) {
    int t = __builtin_amdgcn_update_dpp(0, __float_as_int(v), CTRL, 0xf, 0xf, false);
    return v + __int_as_float(t);
}

__device__ __forceinline__ float group16_sum(float v) {
    v = dpp_add<0xB1>(v);   // quad_perm xor1
    v = dpp_add<0x4E>(v);   // quad_perm xor2
    v = dpp_add<0x141>(v);  // row_half_mirror == xor4 bitwise
    v = dpp_add<0x140>(v);  // row_mirror == xor8 bitwise
    return v;
}

__device__ __forceinline__ float dot4(const float4& a, const float4& b) {
    return a.x * b.x + a.y * b.y + a.z * b.z + a.w * b.w;
}

__device__ __forceinline__ ushort f32_bf16_rne(float f) {
    uint32_t x = __float_as_uint(f);
    return (ushort)((x + 0x7fffu + ((x >> 16) & 1u)) >> 16);
}
__device__ __forceinline__ float bf16_f32(ushort u) {
    return __uint_as_float(((uint32_t)u) << 16);
}
__device__ __forceinline__ float4 cvt4(ushort4 u) {
    return {bf16_f32(u.x), bf16_f32(u.y), bf16_f32(u.z), bf16_f32(u.w)};
}

// ================= bf16-table path =================
// Kernel P: normalize rows, emit bf16 table [N][64] (128 B/row).
__global__ __launch_bounds__(256) void prep_norm_bf16(const float* __restrict__ emb,
                                                      ushort* __restrict__ tab, int N) {
    const int tid = threadIdx.x;
    const int g = tid >> 4, sl = tid & 15;
    const int row = blockIdx.x * 16 + g;
    if (row >= N) return;
    float4 v = *reinterpret_cast<const float4*>(emb + (size_t)row * 64 + sl * 4);
    float ss = dot4(v, v);
    ss = group16_sum(ss);
    const float inv = 1.0f / fmaxf(sqrtf(ss), 1e-12f);
    ushort4 o;
    o.x = f32_bf16_rne(v.x * inv);
    o.y = f32_bf16_rne(v.y * inv);
    o.z = f32_bf16_rne(v.z * inv);
    o.w = f32_bf16_rne(v.w * inv);
    *reinterpret_cast<ushort4*>(tab + (size_t)row * 64 + sl * 4) = o;
}

__global__ __launch_bounds__(256) void edge_loss_bf16(
    const ushort* __restrict__ tab, const int* __restrict__ ei,
    float* __restrict__ partial, int E, uint32_t span, uint32_t mult, uint32_t half,
    uint32_t k1a, uint32_t k1b, uint32_t k2a, uint32_t k2b) {
    const int tid = threadIdx.x;
    const int g = tid >> 4;          // edge within block
    const int sl = tid & 15;         // sublane within group
    const int lane = tid & 63;
    const int e = blockIdx.x * 16 + g;

    float loss = 0.0f;
    if (e < E) {
        const int s = ei[e];
        const int d = ei[E + e];
        const ushort* tp = tab + sl * 4;  // this lane's 8B slice of any row
        const ushort4 su = *reinterpret_cast<const ushort4*>(tp + (size_t)s * 64);
        const ushort4 du = *reinterpret_cast<const ushort4*>(tp + (size_t)d * 64);

        // negative index for slot sl (exact JAX threefry; only sl<10 consumed)
        const int a = min(s, d);
        const int b = max(s, d);
        const uint32_t i = (uint32_t)e * 10u + (uint32_t)sl;
        uint32_t off = draw_bits(k2a, k2b, i, half) % span;
        if (mult != 0u) {
            uint32_t hi = draw_bits(k1a, k1b, i, half) % span;
            off = (hi * mult + off) % span;
        }
        int r = (int)off;
        int r1 = r + (r >= a ? 1 : 0);
        const int negidx = r1 + (((a != b) && (r1 >= b)) ? 1 : 0);

        int idx[10];
        #pragma unroll
        for (int k = 0; k < 10; ++k) idx[k] = __shfl(negidx, (lane & 48) | k);

        ushort4 nu[10];
        #pragma unroll
        for (int k = 0; k < 10; ++k)
            nu[k] = *reinterpret_cast<const ushort4*>(tp + (size_t)idx[k] * 64);

        const float4 sv = cvt4(su);
        const float4 dv = cvt4(du);
        float p = dot4(sv, dv);
        p = group16_sum(p);
        const float pos = p * 2.0f;   // /T, T=0.5 (normalization pre-applied)

        float m = pos;
        float ns[10];
        #pragma unroll
        for (int k = 0; k < 10; ++k) {
            float q = dot4(sv, cvt4(nu[k]));
            q = group16_sum(q);
            const float nsim = q * 2.0f;
            ns[k] = nsim;
            m = fmaxf(m, nsim);
        }
        float ssum = expf(pos - m);
        #pragma unroll
        for (int k = 0; k < 10; ++k) ssum += expf(ns[k] - m);
        const float lse = m + logf(ssum);
        loss = -logf(expf(pos - lse) + 1e-8f);
    }

    float v = (sl == 0) ? loss : 0.0f;
    v += __shfl_xor(v, 16);
    v += __shfl_xor(v, 32);
    __shared__ float sred[4];
    if (lane == 0) sred[tid >> 6] = v;
    __syncthreads();
    if (tid == 0) partial[blockIdx.x] = sred[0] + sred[1] + sred[2] + sred[3];
}

// ================= f32 bit-exact fallback path (round-9, measured 143us) ====
__global__ __launch_bounds__(256) void inv_norm_kernel(const float* __restrict__ emb,
                                                       float* __restrict__ invn, int N) {
    const int tid = threadIdx.x;
    const int g = tid >> 4, sl = tid & 15;
    const int row = blockIdx.x * 16 + g;
    if (row >= N) return;
    float4 v = *reinterpret_cast<const float4*>(emb + (size_t)row * 64 + sl * 4);
    float ss = dot4(v, v);
    ss = group16_sum(ss);
    if (sl == 0) invn[row] = 1.0f / fmaxf(sqrtf(ss), 1e-12f);
}

__global__ __launch_bounds__(256) void edge_loss_kernel(
    const float* __restrict__ emb, const int* __restrict__ ei,
    const float* __restrict__ invn, float* __restrict__ partial,
    int E, uint32_t span, uint32_t mult, uint32_t half,
    uint32_t k1a, uint32_t k1b, uint32_t k2a, uint32_t k2b) {
    const int tid = threadIdx.x;
    const int g = tid >> 4;
    const int sl = tid & 15;
    const int lane = tid & 63;
    const int e = blockIdx.x * 16 + g;

    float loss = 0.0f;
    if (e < E) {
        const int s = ei[e];
        const int d = ei[E + e];
        const float inv_s = invn[s];
        const float inv_d = invn[d];
        const float* rowp = emb + sl * 4;
        const float4 sv = *reinterpret_cast<const float4*>(rowp + (size_t)s * 64);
        const float4 dv = *reinterpret_cast<const float4*>(rowp + (size_t)d * 64);

        const int a = min(s, d);
        const int b = max(s, d);
        const uint32_t i = (uint32_t)e * 10u + (uint32_t)sl;
        uint32_t off = draw_bits(k2a, k2b, i, half) % span;
        if (mult != 0u) {
            uint32_t hi = draw_bits(k1a, k1b, i, half) % span;
            off = (hi * mult + off) % span;
        }
        int r = (int)off;
        int r1 = r + (r >= a ? 1 : 0);
        const int negidx = r1 + (((a != b) && (r1 >= b)) ? 1 : 0);

        int idx[10];
        #pragma unroll
        for (int k = 0; k < 10; ++k) idx[k] = __shfl(negidx, (lane & 48) | k);

        float4 nv[10];
        float ri[10];
        #pragma unroll
        for (int k = 0; k < 10; ++k) {
            nv[k] = *reinterpret_cast<const float4*>(rowp + (size_t)idx[k] * 64);
            ri[k] = invn[idx[k]];
        }

        float p = dot4(sv, dv);
        p = group16_sum(p);
        const float pos = p * inv_s * inv_d * 2.0f;

        float m = pos;
        float ns[10];
        #pragma unroll
        for (int k = 0; k < 10; ++k) {
            float q = dot4(sv, nv[k]);
            q = group16_sum(q);
            const float nsim = q * inv_s * ri[k] * 2.0f;
            ns[k] = nsim;
            m = fmaxf(m, nsim);
        }
        float ssum = expf(pos - m);
        #pragma unroll
        for (int k = 0; k < 10; ++k) ssum += expf(ns[k] - m);
        const float lse = m + logf(ssum);
        loss = -logf(expf(pos - lse) + 1e-8f);
    }

    float v = (sl == 0) ? loss : 0.0f;
    v += __shfl_xor(v, 16);
    v += __shfl_xor(v, 32);
    __shared__ float sred[4];
    if (lane == 0) sred[tid >> 6] = v;
    __syncthreads();
    if (tid == 0) partial[blockIdx.x] = sred[0] + sred[1] + sred[2] + sred[3];
}

// ---------------- final deterministic reduce (double) ----------------
__global__ __launch_bounds__(256) void finalize_kernel(const float* __restrict__ partial,
                                                       int n, float* __restrict__ out) {
    __shared__ double sd[256];
    double acc = 0.0;
    for (int i = threadIdx.x; i < n; i += 256) acc += (double)partial[i];
    sd[threadIdx.x] = acc;
    __syncthreads();
    for (int s = 128; s > 0; s >>= 1) {
        if (threadIdx.x < s) sd[threadIdx.x] += sd[threadIdx.x + s];
        __syncthreads();
    }
    if (threadIdx.x == 0) out[0] = (float)sd[0];
}

extern "C" void kernel_launch(void* const* d_in, const int* in_sizes, int n_in,
                              void* d_out, int out_size, void* d_ws, size_t ws_size,
                              hipStream_t stream) {
    const float* emb = (const float*)d_in[0];
    const int* ei = (const int*)d_in[1];
    const int N = in_sizes[0] / 64;   // 100000
    const int E = in_sizes[1] / 2;    // 400000
    const int K = 10;

    const int nblk_main = (E + 15) / 16;
    const int nblk_norm = (N + 15) / 16;

    const uint32_t span = (uint32_t)(N - 2);
    const uint32_t m0 = 65536u % span;
    const uint32_t mult = (uint32_t)(m0 * m0) % span;   // 0 for span=99998
    const uint32_t half = (uint32_t)((E * K) / 2);

    const size_t tab_bytes = (size_t)N * 64 * sizeof(ushort);            // 12.8 MB
    const size_t tab_pad = (tab_bytes + 255) & ~(size_t)255;
    const size_t need = tab_pad + (size_t)nblk_main * sizeof(float);

    if (ws_size >= need) {
        ushort* tab = (ushort*)d_ws;
        float* partial = (float*)((char*)d_ws + tab_pad);
        prep_norm_bf16<<<nblk_norm, 256, 0, stream>>>(emb, tab, N);
        edge_loss_bf16<<<nblk_main, 256, 0, stream>>>(tab, ei, partial,
                                                      E, span, mult, half,
                                                      KEY_HI.a, KEY_HI.b, KEY_LO.a, KEY_LO.b);
        finalize_kernel<<<1, 256, 0, stream>>>(partial, nblk_main, (float*)d_out);
    } else {
        float* invn = (float*)d_ws;
        float* partial = invn + N;
        inv_norm_kernel<<<nblk_norm, 256, 0, stream>>>(emb, invn, N);
        edge_loss_kernel<<<nblk_main, 256, 0, stream>>>(emb, ei, invn, partial,
                                                        E, span, mult, half,
                                                        KEY_HI.a, KEY_HI.b, KEY_LO.a, KEY_LO.b);
        finalize_kernel<<<1, 256, 0, stream>>>(partial, nblk_main, (float*)d_out);
    }
}